// Round 13
// baseline (199.161 us; speedup 1.0000x reference)
//
#include <hip/hip_runtime.h>
#include <hip/hip_bf16.h>
#include <stdint.h>

#define NN 100000
#define NE 1600000
#define HD 128
#define NG 500
#define NPG 200

#define NBK 782      // node buckets of 128: ceil(NN/128)
#define NBLK 128     // scatter blocks
#define CHUNK 12500  // edges per scatter block (NBLK*CHUNK == NE)
#define NSB 391      // scan blocks over NH = NBK*NBLK entries

typedef __attribute__((ext_vector_type(8))) short short8v;
typedef __attribute__((ext_vector_type(4))) float float4v;
typedef __attribute__((ext_vector_type(2))) float float2v;

// ---------- bf16 helpers (bit-level, RNE) ----------
__device__ __forceinline__ unsigned int packbf(float a, float b) {
  unsigned int ua = __float_as_uint(a), ub = __float_as_uint(b);
  ua += 0x7fffu + ((ua >> 16) & 1u);
  ub += 0x7fffu + ((ub >> 16) & 1u);
  return (ua >> 16) | (ub & 0xffff0000u);
}

// ---------- edge dtype helper (int32 vs int64 detected in-kernel); 4B loads ----------
__device__ __forceinline__ int edge32(const void* p, int is64, int idx) {
  const int* q = (const int*)p;
  return is64 ? q[2 * idx] : q[idx];  // little-endian low word
}

// all 256 threads participate; sf is one LDS int
__device__ __forceinline__ int detect_is64(const void* edges, int tid, int* sf) {
  if (tid == 0) *sf = 0;
  __syncthreads();
  const unsigned int* p = (const unsigned int*)edges;
  unsigned int e = p[2 * tid], o = p[2 * tid + 1];
  unsigned int m = (e ? 1u : 0u) | (o ? 2u : 0u);
  if (m) atomicOr(sf, (int)m);
  __syncthreads();
  int v = *sf;
  return ((v & 2) == 0) && (v & 1);  // all-odd-zero & some-even-nonzero => int64
}

// local exclusive scan of bsums[0..NSB) into sbs[0..NSB) (256 threads, 512 slots)
__device__ __forceinline__ void scan_bsums(const int* __restrict__ bsums, int* sbs, int tid) {
  __shared__ int stmp[512];
  int v0 = (tid < NSB) ? bsums[tid] : 0;
  int v1 = (tid + 256 < NSB) ? bsums[tid + 256] : 0;
  stmp[tid] = v0;
  stmp[tid + 256] = v1;
  __syncthreads();
  for (int off = 1; off < 512; off <<= 1) {
    int t0 = (tid >= off) ? stmp[tid - off] : 0;
    int t1 = (tid + 256 >= off) ? stmp[tid + 256 - off] : 0;
    __syncthreads();
    stmp[tid] += t0;
    stmp[tid + 256] += t1;
    __syncthreads();
  }
  sbs[tid] = stmp[tid] - v0;
  sbs[tid + 256] = stmp[tid + 256] - v1;
  __syncthreads();
}

// ---------- counting sort pass 1: per-(bucket,block) histogram via LDS ----------
__global__ __launch_bounds__(256) void k_hist1(const void* __restrict__ edges,
                                               int* __restrict__ hist) {
  __shared__ int lh[1024];
  __shared__ int sf;
  int tid = threadIdx.x, blk = blockIdx.x;
  int f = detect_is64(edges, tid, &sf);
  for (int i = tid; i < NBK; i += 256) lh[i] = 0;
  __syncthreads();
  int e0 = blk * CHUNK, e1 = e0 + CHUNK;
  if (e1 > NE) e1 = NE;
  for (int e = e0 + tid; e < e1; e += 256) {
    int d = edge32(edges, f, NE + e);
    atomicAdd(&lh[d >> 7], 1);
  }
  __syncthreads();
  for (int i = tid; i < NBK; i += 256) hist[i * NBLK + blk] = lh[i];
}

// ---------- scan: block-exclusive (bsums left raw; consumers re-scan locally) ----------
__global__ void k_scan_block(const int* __restrict__ in, int* __restrict__ outv,
                             int* __restrict__ bsums, int n) {
  __shared__ int s[256];
  int tid = threadIdx.x;
  int i = blockIdx.x * 256 + tid;
  int v = (i < n) ? in[i] : 0;
  s[tid] = v;
  __syncthreads();
  for (int off = 1; off < 256; off <<= 1) {
    int t = (tid >= off) ? s[tid - off] : 0;
    __syncthreads();
    s[tid] += t;
    __syncthreads();
  }
  if (i < n) outv[i] = s[tid] - v;
  if (tid == 255) bsums[blockIdx.x] = s[255];
}

// ---------- counting sort pass 2: scatter records to exact slots ----------
// record = (dst&127)<<17 | src
__global__ __launch_bounds__(256) void k_scatter(const void* __restrict__ edges,
                                                 const int* __restrict__ histS,
                                                 const int* __restrict__ bsums,
                                                 unsigned int* __restrict__ sorted) {
  __shared__ int base[1024];
  __shared__ int sbs[512];
  __shared__ int sf;
  int tid = threadIdx.x, blk = blockIdx.x;
  int f = detect_is64(edges, tid, &sf);
  scan_bsums(bsums, sbs, tid);
  for (int i = tid; i < NBK; i += 256) {
    int idx = i * NBLK + blk;
    base[i] = histS[idx] + sbs[idx >> 8];
  }
  __syncthreads();
  int e0 = blk * CHUNK, e1 = e0 + CHUNK;
  if (e1 > NE) e1 = NE;
  for (int e = e0 + tid; e < e1; e += 256) {
    int s = edge32(edges, f, e);
    int d = edge32(edges, f, NE + e);
    int pos = atomicAdd(&base[d >> 7], 1);
    sorted[pos] = ((unsigned)(d & 127) << 17) | (unsigned)s;
  }
}

// ---------- pass B: bucket records -> node-ordered CSR + rowstart + dinv ----------
__global__ __launch_bounds__(256) void k_passB2(const unsigned int* __restrict__ sorted,
                                                const int* __restrict__ histS,
                                                const int* __restrict__ bsums,
                                                int* __restrict__ rowstart,
                                                float* __restrict__ dinv,
                                                int* __restrict__ csr) {
  __shared__ int sbs[512];
  __shared__ int cnt[128];
  __shared__ int sc[256];
  __shared__ int fill[128];
  __shared__ int stage[4096];
  int b = blockIdx.x, tid = threadIdx.x;
  scan_bsums(bsums, sbs, tid);
  int i0 = b * NBLK;
  int ebase = histS[i0] + sbs[i0 >> 8];
  int eend = NE;
  if (b + 1 < NBK) {
    int i1 = (b + 1) * NBLK;
    eend = histS[i1] + sbs[i1 >> 8];
  }
  int ne = eend - ebase;
  if (tid < 128) { cnt[tid] = 0; fill[tid] = 0; }
  __syncthreads();
  for (int i = tid; i < ne; i += 256) {
    unsigned int r = sorted[ebase + i];
    atomicAdd(&cnt[r >> 17], 1);
  }
  __syncthreads();
  int v = (tid < 128) ? cnt[tid] : 0;
  sc[tid] = v;
  __syncthreads();
  for (int off = 1; off < 256; off <<= 1) {
    int t = (tid >= off) ? sc[tid - off] : 0;
    __syncthreads();
    sc[tid] += t;
    __syncthreads();
  }
  int node = (b << 7) + tid;
  if (tid < 128 && node < NN) {
    rowstart[node] = ebase + sc[tid] - cnt[tid];
    dinv[node] = rsqrtf((float)(cnt[tid] + 1));  // +1 self loop
  }
  if (b == NBK - 1 && tid == 0) rowstart[NN] = NE;
  __syncthreads();
  for (int i = tid; i < ne; i += 256) {
    unsigned int r = sorted[ebase + i];
    int ld = (int)(r >> 17);
    int pos = atomicAdd(&fill[ld], 1);
    stage[sc[ld] - cnt[ld] + pos] = (int)(r & 0x1FFFFu);
  }
  __syncthreads();
  for (int i = tid; i < ne; i += 256) csr[ebase + i] = stage[i];
}

// ---------- merged: per-graph degree order (DESCENDING, LPT) + fp8 convert + W1t + zero pool
__global__ __launch_bounds__(256) void k_ordercvt(const int* __restrict__ rowstart,
                                                  const float* __restrict__ dinv,
                                                  const float4* __restrict__ x,
                                                  uint2* __restrict__ xs8,
                                                  const float* __restrict__ W1,
                                                  unsigned int* __restrict__ W1t,
                                                  int* __restrict__ order,
                                                  float* __restrict__ poolsum) {
  __shared__ int h[128];
  __shared__ int sc[256];
  __shared__ int fill[128];
  __shared__ int degs[256];
  int g = blockIdx.x, tid = threadIdx.x;
  if (tid < 128) { h[tid] = 0; fill[tid] = 0; poolsum[g * 128 + tid] = 0.f; }
  __syncthreads();
  if (tid < NPG) {
    int n = g * NPG + tid;
    int d = rowstart[n + 1] - rowstart[n];
    if (d > 127) d = 127;
    degs[tid] = d;
    atomicAdd(&h[d], 1);
  }
  __syncthreads();
  int v = (tid < 128) ? h[tid] : 0;
  sc[tid] = v;
  __syncthreads();
  for (int off = 1; off < 256; off <<= 1) {
    int t = (tid >= off) ? sc[tid - off] : 0;
    __syncthreads();
    sc[tid] += t;
    __syncthreads();
  }
  if (tid < NPG) {
    int d = degs[tid];
    int pos = sc[d] - h[d] + atomicAdd(&fill[d], 1);
    order[g * NPG + (NPG - 1 - pos)] = g * NPG + tid;  // descending degree (LPT)
  }
  // fp8 convert: xs8[node] = fp8(8 * dinv[node] * x[node]) for this graph's nodes
  for (int idx = tid; idx < NPG * 16; idx += 256) {
    int node = g * NPG + (idx >> 4);
    int l = idx & 15;
    float s = dinv[node] * 8.f;
    float4 a = x[(size_t)node * 32 + l * 2];
    float4 b = x[(size_t)node * 32 + l * 2 + 1];
    int w0 = __builtin_amdgcn_cvt_pk_fp8_f32(a.x * s, a.y * s, 0, false);
    w0 = __builtin_amdgcn_cvt_pk_fp8_f32(a.z * s, a.w * s, w0, true);
    int w1 = __builtin_amdgcn_cvt_pk_fp8_f32(b.x * s, b.y * s, 0, false);
    w1 = __builtin_amdgcn_cvt_pk_fp8_f32(b.z * s, b.w * s, w1, true);
    xs8[(size_t)node * 16 + l] = make_uint2((unsigned)w0, (unsigned)w1);
  }
  // W1 -> bf16 transposed W1t[c][kp] (8192 entries over blocks 0..31)
  if (g < 32) {
    int e = g * 256 + tid;
    int c = e >> 6, kp = e & 63;
    float w0 = W1[(size_t)(2 * kp) * 128 + c];
    float w1 = W1[(size_t)(2 * kp + 1) * 128 + c];
    W1t[c * 64 + kp] = packbf(w0, w1);
  }
}

// ---------- fp8 gather-aggregate core: 16 lanes/node, uint2 (8 fp8 ch)/lane ----------
__device__ __forceinline__ void accf8(float* a, uint2 v) {
  float2v f;
  f = __builtin_amdgcn_cvt_pk_f32_fp8((int)v.x, false); a[0] += f.x; a[1] += f.y;
  f = __builtin_amdgcn_cvt_pk_f32_fp8((int)v.x, true);  a[2] += f.x; a[3] += f.y;
  f = __builtin_amdgcn_cvt_pk_f32_fp8((int)v.y, false); a[4] += f.x; a[5] += f.y;
  f = __builtin_amdgcn_cvt_pk_f32_fp8((int)v.y, true);  a[6] += f.x; a[7] += f.y;
}

// 8/4/1 unroll ladder (r6-proven: VGPR 36)
#define AGG_CORE8(IN, NODE, L, A)                                                \
  float A[8] = {0.f, 0.f, 0.f, 0.f, 0.f, 0.f, 0.f, 0.f};                         \
  accf8(A, IN[(size_t)(NODE)*16 + (L)]);                                         \
  {                                                                              \
    int i = rowstart[NODE], end = rowstart[(NODE) + 1];                          \
    for (; i + 7 < end; i += 8) {                                                \
      int s0 = csr[i], s1 = csr[i + 1], s2 = csr[i + 2], s3 = csr[i + 3];        \
      int s4 = csr[i + 4], s5 = csr[i + 5], s6 = csr[i + 6], s7 = csr[i + 7];    \
      uint2 v0 = IN[(size_t)s0 * 16 + (L)];                                      \
      uint2 v1 = IN[(size_t)s1 * 16 + (L)];                                      \
      uint2 v2 = IN[(size_t)s2 * 16 + (L)];                                      \
      uint2 v3 = IN[(size_t)s3 * 16 + (L)];                                      \
      uint2 v4 = IN[(size_t)s4 * 16 + (L)];                                      \
      uint2 v5 = IN[(size_t)s5 * 16 + (L)];                                      \
      uint2 v6 = IN[(size_t)s6 * 16 + (L)];                                      \
      uint2 v7 = IN[(size_t)s7 * 16 + (L)];                                      \
      accf8(A, v0); accf8(A, v1); accf8(A, v2); accf8(A, v3);                    \
      accf8(A, v4); accf8(A, v5); accf8(A, v6); accf8(A, v7);                    \
    }                                                                            \
    for (; i + 3 < end; i += 4) {                                                \
      int s0 = csr[i], s1 = csr[i + 1], s2 = csr[i + 2], s3 = csr[i + 3];        \
      uint2 v0 = IN[(size_t)s0 * 16 + (L)];                                      \
      uint2 v1 = IN[(size_t)s1 * 16 + (L)];                                      \
      uint2 v2 = IN[(size_t)s2 * 16 + (L)];                                      \
      uint2 v3 = IN[(size_t)s3 * 16 + (L)];                                      \
      accf8(A, v0); accf8(A, v1); accf8(A, v2); accf8(A, v3);                    \
    }                                                                            \
    for (; i < end; ++i) {                                                       \
      uint2 v0 = IN[(size_t)csr[i] * 16 + (L)];                                  \
      accf8(A, v0);                                                              \
    }                                                                            \
  }

// ---------- fused agg1 + GEMM1 (MFMA): h1s8[v] = fp8(16*dinv*relu(Agg(x)@W1+b1)) ----------
// LDS shrunk to 8 KB: At (4 KB) and Ot (8 KB) share one buffer (disjoint live ranges).
__global__ __launch_bounds__(256) void k_agg1g(const uint2* __restrict__ in,
                                               const unsigned int* __restrict__ W1t,
                                               const float* __restrict__ bias,
                                               uint2* __restrict__ out,
                                               const int* __restrict__ rowstart,
                                               const int* __restrict__ csr,
                                               const float* __restrict__ dinv,
                                               const int* __restrict__ order) {
  __shared__ char buf[8192];  // union: bf16 A-tile (4KB) then f32 out-tile (8KB)
  int tid = threadIdx.x;
  int qw = tid >> 4, l = tid & 15;
  int pos = blockIdx.x * 16 + qw;
  int node = order[pos];
  AGG_CORE8(in, node, l, a)
  float dv = dinv[node];
  {
    float ds = dv * 0.125f;  // undo the 8x input prescale
    uint4 o;
    o.x = packbf(a[0] * ds, a[1] * ds); o.y = packbf(a[2] * ds, a[3] * ds);
    o.z = packbf(a[4] * ds, a[5] * ds); o.w = packbf(a[6] * ds, a[7] * ds);
    ((uint4*)buf)[qw * 16 + (l ^ (qw & 7))] = o;  // At
  }
  __syncthreads();

  // MFMA: wave w covers col-tiles {2w, 2w+1}
  int w = tid >> 6, lane = tid & 63;
  int m = lane & 15, g = lane >> 4;
  float4v acc[2];
  acc[0] = (float4v)0.f;
  acc[1] = (float4v)0.f;
#pragma unroll
  for (int ks = 0; ks < 4; ++ks) {
    int slot = ks * 4 + g;
    short8v af = *(const short8v*)&((const uint4*)buf)[m * 16 + (slot ^ (m & 7))];
#pragma unroll
    for (int t = 0; t < 2; ++t) {
      int c = (w * 2 + t) * 16 + m;
      short8v bf = *(const short8v*)&W1t[c * 64 + ks * 16 + g * 4];
      acc[t] = __builtin_amdgcn_mfma_f32_16x16x32_bf16(af, bf, acc[t], 0, 0, 0);
    }
  }
  __syncthreads();  // all At reads done before buf is reused as Ot

  // per-row scale 16*dinv for this lane's 4 output rows (L2-hit reloads)
  float dvr[4];
#pragma unroll
  for (int j = 0; j < 4; ++j) dvr[j] = dinv[order[blockIdx.x * 16 + g * 4 + j]] * 16.f;

  // epilogue: bias + relu + prescale -> swizzled f32 tile in buf
#pragma unroll
  for (int t = 0; t < 2; ++t) {
    int c = (w * 2 + t) * 16 + m;
    float bl = bias[c];
#pragma unroll
    for (int j = 0; j < 4; ++j) {
      int r = g * 4 + j;
      float v = fmaxf(acc[t][j] + bl, 0.f) * dvr[j];
      *(float*)(buf + r * 512 + ((c * 4) ^ ((r & 7) << 4))) = v;
    }
  }
  __syncthreads();
  // readout: quarter-wave qw streams row qw, packs fp8
  {
    int s = (qw & 7) << 4;
    const char* base = buf + qw * 512;
    float4 f0 = *(const float4*)(base + ((l * 32) ^ s));
    float4 f1 = *(const float4*)(base + ((l * 32 + 16) ^ s));
    int w0 = __builtin_amdgcn_cvt_pk_fp8_f32(f0.x, f0.y, 0, false);
    w0 = __builtin_amdgcn_cvt_pk_fp8_f32(f0.z, f0.w, w0, true);
    int w1 = __builtin_amdgcn_cvt_pk_fp8_f32(f1.x, f1.y, 0, false);
    w1 = __builtin_amdgcn_cvt_pk_fp8_f32(f1.z, f1.w, w1, true);
    out[(size_t)node * 16 + l] = make_uint2((unsigned)w0, (unsigned)w1);
  }
}

// agg2 + fused per-graph sum pool. LDS shrunk to 2 KB via wave-level shuffle pre-reduce.
// Graph boundary offset within a block is a multiple of 8 (200%16==8), i.e. at a wave
// boundary (4 nodes/wave) -> wave reduction never mixes graphs.
__global__ __launch_bounds__(256) void k_agg2p(const uint2* __restrict__ in,
                                               float* __restrict__ poolsum,
                                               const int* __restrict__ rowstart,
                                               const int* __restrict__ csr,
                                               const float* __restrict__ dinv,
                                               const int* __restrict__ order) {
  __shared__ float sh[4][128];
  int nl = threadIdx.x >> 4, l = threadIdx.x & 15;
  int pos = blockIdx.x * 16 + nl;
  int node = order[pos];
  AGG_CORE8(in, node, l, a)
  float dv = dinv[node];
#pragma unroll
  for (int j = 0; j < 8; ++j) a[j] *= dv;
  // reduce the wave's 4 nodes (quarter-waves) in-register
#pragma unroll
  for (int j = 0; j < 8; ++j) {
    a[j] += __shfl_xor(a[j], 16);
    a[j] += __shfl_xor(a[j], 32);
  }
  int w = threadIdx.x >> 6, lane = threadIdx.x & 63;
  if (lane < 16) {
    *(float4*)&sh[w][lane * 8] = make_float4(a[0], a[1], a[2], a[3]);
    *(float4*)&sh[w][lane * 8 + 4] = make_float4(a[4], a[5], a[6], a[7]);
  }
  __syncthreads();
  int tid = threadIdx.x;
  if (tid < 128) {
    int n0 = blockIdx.x * 16;
    int gA = n0 / NPG;
    int split = (gA + 1) * NPG - n0;  // node positions [0,split) belong to gA
    if (split > 16) split = 16;
    int splitw = split >> 2;          // split in {8,16} -> wave count {2,4}
    float sA = 0.f, sB = 0.f;
#pragma unroll
    for (int wv = 0; wv < 4; ++wv) {
      float v = sh[wv][tid];
      if (wv < splitw) sA += v; else sB += v;
    }
    atomicAdd(&poolsum[gA * 128 + tid], sA);
    if (split < 16) atomicAdd(&poolsum[(gA + 1) * 128 + tid], sB);
  }
}

// ---------- GEMM2 small-M: out[M x 128] = (A*ascale) @ W + bias, 8 rows/block ----------
__global__ __launch_bounds__(256) void k_gemm2s(const float* __restrict__ A,
                                                const float* __restrict__ W,
                                                const float* __restrict__ bias,
                                                float* __restrict__ out, int M, float ascale) {
  __shared__ float As[8][128];
  int tid = threadIdx.x;
  int row0 = blockIdx.x * 8;
  {
    int r = tid >> 5, c4 = (tid & 31) * 4;
    float4 v = make_float4(0.f, 0.f, 0.f, 0.f);
    if (row0 + r < M) v = *(const float4*)&A[(size_t)(row0 + r) * 128 + c4];
    *(float4*)&As[r][c4] = make_float4(v.x * ascale, v.y * ascale, v.z * ascale, v.w * ascale);
  }
  __syncthreads();
  int r = tid >> 5, c0 = (tid & 31) * 4;
  float acc0 = 0.f, acc1 = 0.f, acc2 = 0.f, acc3 = 0.f;
  for (int k = 0; k < 128; ++k) {
    float a = As[r][k];
    float4 wv = *(const float4*)&W[(size_t)k * 128 + c0];
    acc0 = fmaf(a, wv.x, acc0); acc1 = fmaf(a, wv.y, acc1);
    acc2 = fmaf(a, wv.z, acc2); acc3 = fmaf(a, wv.w, acc3);
  }
  if (row0 + r < M) {
    float4 o;
    o.x = acc0 + bias[c0]; o.y = acc1 + bias[c0 + 1];
    o.z = acc2 + bias[c0 + 2]; o.w = acc3 + bias[c0 + 3];
    *(float4*)&out[(size_t)(row0 + r) * 128 + c0] = o;
  }
}

extern "C" void kernel_launch(void* const* d_in, const int* in_sizes, int n_in,
                              void* d_out, int out_size, void* d_ws, size_t ws_size,
                              hipStream_t stream) {
  const float* x  = (const float*)d_in[0];
  const void* edges = d_in[1];
  const float* W1 = (const float*)d_in[3];
  const float* b1 = (const float*)d_in[4];
  const float* W2 = (const float*)d_in[5];
  const float* b2 = (const float*)d_in[6];
  float* out = (float*)d_out;

  // workspace layout (bytes), ~40.7 MB total
  char* ws = (char*)d_ws;
  float* poolsum  = (float*)(ws + 0);          // 256000  (zeroed in k_ordercvt)
  int*   hist     = (int*)(ws + 256000);       // 400384
  int*   histS    = (int*)(ws + 656384);       // 400384 (block-exclusive)
  int*   bsums    = (int*)(ws + 1056768);      // 2048   (raw block sums)
  int*   rowstart = (int*)(ws + 1058816);      // 400016
  float* dinv     = (float*)(ws + 1458832);    // 400000
  int*   order    = (int*)(ws + 1858832);      // 400000
  unsigned int* W1t = (unsigned int*)(ws + 2258832);     // 32768 (bf16 W1^T)
  unsigned int* sorted = (unsigned int*)(ws + 2291600);  // 6.4 MB
  int*   csr      = (int*)(ws + 8691600);      // 6.4 MB
  void*  xs8      = (void*)(ws + 15091600);    // 12.8 MB  fp8(8*dinv*x)
  void*  h1s8     = (void*)(ws + 27891600);    // 12.8 MB  fp8(16*dinv*h1)

  const int NH = NBK * NBLK;  // 100096 histogram entries

  k_hist1<<<NBLK, 256, 0, stream>>>(edges, hist);
  k_scan_block<<<NSB, 256, 0, stream>>>(hist, histS, bsums, NH);
  k_scatter<<<NBLK, 256, 0, stream>>>(edges, histS, bsums, sorted);
  k_passB2<<<NBK, 256, 0, stream>>>(sorted, histS, bsums, rowstart, dinv, csr);
  // order (descending degree, LPT) + xs8 = fp8(8*dinv*x) + W1t = bf16(W1^T) + zero poolsum
  k_ordercvt<<<NG, 256, 0, stream>>>(rowstart, dinv, (const float4*)x, (uint2*)xs8,
                                     W1, W1t, order, poolsum);

  // conv1 fused: h1s8 = fp8( 16 * dinv * relu( Agg(x) @ W1 + b1 ) )
  k_agg1g<<<NN / 16, 256, 0, stream>>>((const uint2*)xs8, W1t, b1, (uint2*)h1s8,
                                       rowstart, csr, dinv, order);
  // conv2 fused with pool: poolsum = 16 * sum_graph( dinv*(h1s self+gather) )
  k_agg2p<<<NN / 16, 256, 0, stream>>>((const uint2*)h1s8, poolsum, rowstart, csr, dinv, order);
  // out = (poolsum/(200*16)) @ W2 + b2
  k_gemm2s<<<(NG + 7) / 8, 256, 0, stream>>>(poolsum, W2, b2, out, NG, 1.f / 3200.f);
}

// Round 14
// 194.439 us; speedup vs baseline: 1.0243x; 1.0243x over previous
//
#include <hip/hip_runtime.h>
#include <hip/hip_bf16.h>
#include <stdint.h>

#define NN 100000
#define NE 1600000
#define HD 128
#define NG 500
#define NPG 200

#define NBK 782      // node buckets of 128: ceil(NN/128)
#define NBLK 128     // scatter blocks
#define CHUNK 12500  // edges per scatter block (NBLK*CHUNK == NE)
#define NSB 391      // scan blocks over NH = NBK*NBLK entries

typedef __attribute__((ext_vector_type(8))) short short8v;
typedef __attribute__((ext_vector_type(4))) float float4v;
typedef __attribute__((ext_vector_type(2))) float float2v;

// ---------- bf16 helpers (bit-level, RNE) ----------
__device__ __forceinline__ unsigned int packbf(float a, float b) {
  unsigned int ua = __float_as_uint(a), ub = __float_as_uint(b);
  ua += 0x7fffu + ((ua >> 16) & 1u);
  ub += 0x7fffu + ((ub >> 16) & 1u);
  return (ua >> 16) | (ub & 0xffff0000u);
}

// ---------- edge dtype helper (int32 vs int64 detected in-kernel); 4B loads ----------
__device__ __forceinline__ int edge32(const void* p, int is64, int idx) {
  const int* q = (const int*)p;
  return is64 ? q[2 * idx] : q[idx];  // little-endian low word
}

// all 256 threads participate; sf is one LDS int
__device__ __forceinline__ int detect_is64(const void* edges, int tid, int* sf) {
  if (tid == 0) *sf = 0;
  __syncthreads();
  const unsigned int* p = (const unsigned int*)edges;
  unsigned int e = p[2 * tid], o = p[2 * tid + 1];
  unsigned int m = (e ? 1u : 0u) | (o ? 2u : 0u);
  if (m) atomicOr(sf, (int)m);
  __syncthreads();
  int v = *sf;
  return ((v & 2) == 0) && (v & 1);  // all-odd-zero & some-even-nonzero => int64
}

// local exclusive scan of bsums[0..NSB) into sbs[0..NSB) (256 threads, 512 slots)
__device__ __forceinline__ void scan_bsums(const int* __restrict__ bsums, int* sbs, int tid) {
  __shared__ int stmp[512];
  int v0 = (tid < NSB) ? bsums[tid] : 0;
  int v1 = (tid + 256 < NSB) ? bsums[tid + 256] : 0;
  stmp[tid] = v0;
  stmp[tid + 256] = v1;
  __syncthreads();
  for (int off = 1; off < 512; off <<= 1) {
    int t0 = (tid >= off) ? stmp[tid - off] : 0;
    int t1 = (tid + 256 >= off) ? stmp[tid + 256 - off] : 0;
    __syncthreads();
    stmp[tid] += t0;
    stmp[tid + 256] += t1;
    __syncthreads();
  }
  sbs[tid] = stmp[tid] - v0;
  sbs[tid + 256] = stmp[tid + 256] - v1;
  __syncthreads();
}

// ---------- counting sort pass 1: per-(bucket,block) histogram via LDS ----------
__global__ __launch_bounds__(256) void k_hist1(const void* __restrict__ edges,
                                               int* __restrict__ hist) {
  __shared__ int lh[1024];
  __shared__ int sf;
  int tid = threadIdx.x, blk = blockIdx.x;
  int f = detect_is64(edges, tid, &sf);
  for (int i = tid; i < NBK; i += 256) lh[i] = 0;
  __syncthreads();
  int e0 = blk * CHUNK, e1 = e0 + CHUNK;
  if (e1 > NE) e1 = NE;
  for (int e = e0 + tid; e < e1; e += 256) {
    int d = edge32(edges, f, NE + e);
    atomicAdd(&lh[d >> 7], 1);
  }
  __syncthreads();
  for (int i = tid; i < NBK; i += 256) hist[i * NBLK + blk] = lh[i];
}

// ---------- scan: block-exclusive (bsums left raw; consumers re-scan locally) ----------
__global__ void k_scan_block(const int* __restrict__ in, int* __restrict__ outv,
                             int* __restrict__ bsums, int n) {
  __shared__ int s[256];
  int tid = threadIdx.x;
  int i = blockIdx.x * 256 + tid;
  int v = (i < n) ? in[i] : 0;
  s[tid] = v;
  __syncthreads();
  for (int off = 1; off < 256; off <<= 1) {
    int t = (tid >= off) ? s[tid - off] : 0;
    __syncthreads();
    s[tid] += t;
    __syncthreads();
  }
  if (i < n) outv[i] = s[tid] - v;
  if (tid == 255) bsums[blockIdx.x] = s[255];
}

// ---------- counting sort pass 2: scatter records to exact slots ----------
// record = (dst&127)<<17 | src
__global__ __launch_bounds__(256) void k_scatter(const void* __restrict__ edges,
                                                 const int* __restrict__ histS,
                                                 const int* __restrict__ bsums,
                                                 unsigned int* __restrict__ sorted) {
  __shared__ int base[1024];
  __shared__ int sbs[512];
  __shared__ int sf;
  int tid = threadIdx.x, blk = blockIdx.x;
  int f = detect_is64(edges, tid, &sf);
  scan_bsums(bsums, sbs, tid);
  for (int i = tid; i < NBK; i += 256) {
    int idx = i * NBLK + blk;
    base[i] = histS[idx] + sbs[idx >> 8];
  }
  __syncthreads();
  int e0 = blk * CHUNK, e1 = e0 + CHUNK;
  if (e1 > NE) e1 = NE;
  for (int e = e0 + tid; e < e1; e += 256) {
    int s = edge32(edges, f, e);
    int d = edge32(edges, f, NE + e);
    int pos = atomicAdd(&base[d >> 7], 1);
    sorted[pos] = ((unsigned)(d & 127) << 17) | (unsigned)s;
  }
}

// ---------- pass B: bucket records -> node-ordered CSR + rowstart + dinv ----------
__global__ __launch_bounds__(256) void k_passB2(const unsigned int* __restrict__ sorted,
                                                const int* __restrict__ histS,
                                                const int* __restrict__ bsums,
                                                int* __restrict__ rowstart,
                                                float* __restrict__ dinv,
                                                int* __restrict__ csr) {
  __shared__ int sbs[512];
  __shared__ int cnt[128];
  __shared__ int sc[256];
  __shared__ int fill[128];
  __shared__ int stage[4096];
  int b = blockIdx.x, tid = threadIdx.x;
  scan_bsums(bsums, sbs, tid);
  int i0 = b * NBLK;
  int ebase = histS[i0] + sbs[i0 >> 8];
  int eend = NE;
  if (b + 1 < NBK) {
    int i1 = (b + 1) * NBLK;
    eend = histS[i1] + sbs[i1 >> 8];
  }
  int ne = eend - ebase;
  if (tid < 128) { cnt[tid] = 0; fill[tid] = 0; }
  __syncthreads();
  for (int i = tid; i < ne; i += 256) {
    unsigned int r = sorted[ebase + i];
    atomicAdd(&cnt[r >> 17], 1);
  }
  __syncthreads();
  int v = (tid < 128) ? cnt[tid] : 0;
  sc[tid] = v;
  __syncthreads();
  for (int off = 1; off < 256; off <<= 1) {
    int t = (tid >= off) ? sc[tid - off] : 0;
    __syncthreads();
    sc[tid] += t;
    __syncthreads();
  }
  int node = (b << 7) + tid;
  if (tid < 128 && node < NN) {
    rowstart[node] = ebase + sc[tid] - cnt[tid];
    dinv[node] = rsqrtf((float)(cnt[tid] + 1));  // +1 self loop
  }
  if (b == NBK - 1 && tid == 0) rowstart[NN] = NE;
  __syncthreads();
  for (int i = tid; i < ne; i += 256) {
    unsigned int r = sorted[ebase + i];
    int ld = (int)(r >> 17);
    int pos = atomicAdd(&fill[ld], 1);
    stage[sc[ld] - cnt[ld] + pos] = (int)(r & 0x1FFFFu);
  }
  __syncthreads();
  for (int i = tid; i < ne; i += 256) csr[ebase + i] = stage[i];
}

// ---------- merged: per-graph degree order (DESCENDING, LPT) + fp8 convert + W1t + zero pool
__global__ __launch_bounds__(256) void k_ordercvt(const int* __restrict__ rowstart,
                                                  const float* __restrict__ dinv,
                                                  const float4* __restrict__ x,
                                                  uint2* __restrict__ xs8,
                                                  const float* __restrict__ W1,
                                                  unsigned int* __restrict__ W1t,
                                                  int* __restrict__ order,
                                                  float* __restrict__ poolsum) {
  __shared__ int h[128];
  __shared__ int sc[256];
  __shared__ int fill[128];
  __shared__ int degs[256];
  int g = blockIdx.x, tid = threadIdx.x;
  if (tid < 128) { h[tid] = 0; fill[tid] = 0; poolsum[g * 128 + tid] = 0.f; }
  __syncthreads();
  if (tid < NPG) {
    int n = g * NPG + tid;
    int d = rowstart[n + 1] - rowstart[n];
    if (d > 127) d = 127;
    degs[tid] = d;
    atomicAdd(&h[d], 1);
  }
  __syncthreads();
  int v = (tid < 128) ? h[tid] : 0;
  sc[tid] = v;
  __syncthreads();
  for (int off = 1; off < 256; off <<= 1) {
    int t = (tid >= off) ? sc[tid - off] : 0;
    __syncthreads();
    sc[tid] += t;
    __syncthreads();
  }
  if (tid < NPG) {
    int d = degs[tid];
    int pos = sc[d] - h[d] + atomicAdd(&fill[d], 1);
    order[g * NPG + (NPG - 1 - pos)] = g * NPG + tid;  // descending degree (LPT)
  }
  // fp8 convert: xs8[node] = fp8(8 * dinv[node] * x[node]) for this graph's nodes
  for (int idx = tid; idx < NPG * 16; idx += 256) {
    int node = g * NPG + (idx >> 4);
    int l = idx & 15;
    float s = dinv[node] * 8.f;
    float4 a = x[(size_t)node * 32 + l * 2];
    float4 b = x[(size_t)node * 32 + l * 2 + 1];
    int w0 = __builtin_amdgcn_cvt_pk_fp8_f32(a.x * s, a.y * s, 0, false);
    w0 = __builtin_amdgcn_cvt_pk_fp8_f32(a.z * s, a.w * s, w0, true);
    int w1 = __builtin_amdgcn_cvt_pk_fp8_f32(b.x * s, b.y * s, 0, false);
    w1 = __builtin_amdgcn_cvt_pk_fp8_f32(b.z * s, b.w * s, w1, true);
    xs8[(size_t)node * 16 + l] = make_uint2((unsigned)w0, (unsigned)w1);
  }
  // W1 -> bf16 transposed W1t[c][kp] (8192 entries over blocks 0..31)
  if (g < 32) {
    int e = g * 256 + tid;
    int c = e >> 6, kp = e & 63;
    float w0 = W1[(size_t)(2 * kp) * 128 + c];
    float w1 = W1[(size_t)(2 * kp + 1) * 128 + c];
    W1t[c * 64 + kp] = packbf(w0, w1);
  }
}

// ---------- fp8 gather-aggregate core: 16 lanes/node, uint2 (8 fp8 ch)/lane ----------
__device__ __forceinline__ void accf8(float* a, uint2 v) {
  float2v f;
  f = __builtin_amdgcn_cvt_pk_f32_fp8((int)v.x, false); a[0] += f.x; a[1] += f.y;
  f = __builtin_amdgcn_cvt_pk_f32_fp8((int)v.x, true);  a[2] += f.x; a[3] += f.y;
  f = __builtin_amdgcn_cvt_pk_f32_fp8((int)v.y, false); a[4] += f.x; a[5] += f.y;
  f = __builtin_amdgcn_cvt_pk_f32_fp8((int)v.y, true);  a[6] += f.x; a[7] += f.y;
}

// 8/4/1 unroll ladder (r6-proven: VGPR 36, occ ~62%)
#define AGG_CORE8(IN, NODE, L, A)                                                \
  float A[8] = {0.f, 0.f, 0.f, 0.f, 0.f, 0.f, 0.f, 0.f};                         \
  accf8(A, IN[(size_t)(NODE)*16 + (L)]);                                         \
  {                                                                              \
    int i = rowstart[NODE], end = rowstart[(NODE) + 1];                          \
    for (; i + 7 < end; i += 8) {                                                \
      int s0 = csr[i], s1 = csr[i + 1], s2 = csr[i + 2], s3 = csr[i + 3];        \
      int s4 = csr[i + 4], s5 = csr[i + 5], s6 = csr[i + 6], s7 = csr[i + 7];    \
      uint2 v0 = IN[(size_t)s0 * 16 + (L)];                                      \
      uint2 v1 = IN[(size_t)s1 * 16 + (L)];                                      \
      uint2 v2 = IN[(size_t)s2 * 16 + (L)];                                      \
      uint2 v3 = IN[(size_t)s3 * 16 + (L)];                                      \
      uint2 v4 = IN[(size_t)s4 * 16 + (L)];                                      \
      uint2 v5 = IN[(size_t)s5 * 16 + (L)];                                      \
      uint2 v6 = IN[(size_t)s6 * 16 + (L)];                                      \
      uint2 v7 = IN[(size_t)s7 * 16 + (L)];                                      \
      accf8(A, v0); accf8(A, v1); accf8(A, v2); accf8(A, v3);                    \
      accf8(A, v4); accf8(A, v5); accf8(A, v6); accf8(A, v7);                    \
    }                                                                            \
    for (; i + 3 < end; i += 4) {                                                \
      int s0 = csr[i], s1 = csr[i + 1], s2 = csr[i + 2], s3 = csr[i + 3];        \
      uint2 v0 = IN[(size_t)s0 * 16 + (L)];                                      \
      uint2 v1 = IN[(size_t)s1 * 16 + (L)];                                      \
      uint2 v2 = IN[(size_t)s2 * 16 + (L)];                                      \
      uint2 v3 = IN[(size_t)s3 * 16 + (L)];                                      \
      accf8(A, v0); accf8(A, v1); accf8(A, v2); accf8(A, v3);                    \
    }                                                                            \
    for (; i < end; ++i) {                                                       \
      uint2 v0 = IN[(size_t)csr[i] * 16 + (L)];                                  \
      accf8(A, v0);                                                              \
    }                                                                            \
  }

// ---------- fused agg1 + GEMM1 (MFMA): h1s8[v] = fp8(16*dinv*relu(Agg(x)@W1+b1)) ----------
__global__ __launch_bounds__(256) void k_agg1g(const uint2* __restrict__ in,
                                               const unsigned int* __restrict__ W1t,
                                               const float* __restrict__ bias,
                                               uint2* __restrict__ out,
                                               const int* __restrict__ rowstart,
                                               const int* __restrict__ csr,
                                               const float* __restrict__ dinv,
                                               const int* __restrict__ order) {
  __shared__ uint4 At[16 * 16];   // bf16 A-tile, row r chunk s at At[r*16 + (s^(r&7))]
  __shared__ float Ot[16 * 128];  // f32 out-tile, elem (r,c) at byte r*512 + ((c*4)^((r&7)<<4))
  __shared__ float sdv[16];
  int tid = threadIdx.x;
  int qw = tid >> 4, l = tid & 15;
  int pos = blockIdx.x * 16 + qw;
  int node = order[pos];
  AGG_CORE8(in, node, l, a)
  float dv = dinv[node];
  if (l == 0) sdv[qw] = dv;
  {
    float ds = dv * 0.125f;  // undo the 8x input prescale
    uint4 o;
    o.x = packbf(a[0] * ds, a[1] * ds); o.y = packbf(a[2] * ds, a[3] * ds);
    o.z = packbf(a[4] * ds, a[5] * ds); o.w = packbf(a[6] * ds, a[7] * ds);
    At[qw * 16 + (l ^ (qw & 7))] = o;
  }
  __syncthreads();

  // MFMA: wave w covers col-tiles {2w, 2w+1}
  int w = tid >> 6, lane = tid & 63;
  int m = lane & 15, g = lane >> 4;
  float4v acc[2];
  acc[0] = (float4v)0.f;
  acc[1] = (float4v)0.f;
#pragma unroll
  for (int ks = 0; ks < 4; ++ks) {
    int slot = ks * 4 + g;
    short8v af = *(const short8v*)&At[m * 16 + (slot ^ (m & 7))];
#pragma unroll
    for (int t = 0; t < 2; ++t) {
      int c = (w * 2 + t) * 16 + m;
      short8v bf = *(const short8v*)&W1t[c * 64 + ks * 16 + g * 4];
      acc[t] = __builtin_amdgcn_mfma_f32_16x16x32_bf16(af, bf, acc[t], 0, 0, 0);
    }
  }
  // epilogue: bias + relu + (16*dinv) prescale -> swizzled f32 tile
#pragma unroll
  for (int t = 0; t < 2; ++t) {
    int c = (w * 2 + t) * 16 + m;
    float bl = bias[c];
#pragma unroll
    for (int j = 0; j < 4; ++j) {
      int r = g * 4 + j;
      float v = fmaxf(acc[t][j] + bl, 0.f) * (sdv[r] * 16.f);
      *(float*)((char*)Ot + r * 512 + ((c * 4) ^ ((r & 7) << 4))) = v;
    }
  }
  __syncthreads();
  // readout: quarter-wave qw streams row qw, packs fp8
  {
    int s = (qw & 7) << 4;
    const char* base = (const char*)Ot + qw * 512;
    float4 f0 = *(const float4*)(base + ((l * 32) ^ s));
    float4 f1 = *(const float4*)(base + ((l * 32 + 16) ^ s));
    int w0 = __builtin_amdgcn_cvt_pk_fp8_f32(f0.x, f0.y, 0, false);
    w0 = __builtin_amdgcn_cvt_pk_fp8_f32(f0.z, f0.w, w0, true);
    int w1 = __builtin_amdgcn_cvt_pk_fp8_f32(f1.x, f1.y, 0, false);
    w1 = __builtin_amdgcn_cvt_pk_fp8_f32(f1.z, f1.w, w1, true);
    out[(size_t)node * 16 + l] = make_uint2((unsigned)w0, (unsigned)w1);
  }
}

// agg2 + fused per-graph sum pool. Input h1s8 = fp8(16*h1s_true); poolsum = 16*true sums.
__global__ __launch_bounds__(256) void k_agg2p(const uint2* __restrict__ in,
                                               float* __restrict__ poolsum,
                                               const int* __restrict__ rowstart,
                                               const int* __restrict__ csr,
                                               const float* __restrict__ dinv,
                                               const int* __restrict__ order) {
  __shared__ float sh[16][128];
  int nl = threadIdx.x >> 4, l = threadIdx.x & 15;
  int pos = blockIdx.x * 16 + nl;
  int node = order[pos];
  AGG_CORE8(in, node, l, a)
  float dv = dinv[node];
#pragma unroll
  for (int j = 0; j < 8; ++j) a[j] *= dv;
  *(float4*)&sh[nl][l * 8] = make_float4(a[0], a[1], a[2], a[3]);
  *(float4*)&sh[nl][l * 8 + 4] = make_float4(a[4], a[5], a[6], a[7]);
  __syncthreads();
  int tid = threadIdx.x;
  if (tid < 128) {
    int n0 = blockIdx.x * 16;
    int gA = n0 / NPG;
    int split = (gA + 1) * NPG - n0;  // positions [0,split) belong to gA
    if (split > 16) split = 16;
    float sA = 0.f, sB = 0.f;
#pragma unroll
    for (int n = 0; n < 16; ++n) {
      float v = sh[n][tid];
      if (n < split) sA += v; else sB += v;
    }
    atomicAdd(&poolsum[gA * 128 + tid], sA);
    if (split < 16) atomicAdd(&poolsum[(gA + 1) * 128 + tid], sB);
  }
}

// ---------- GEMM2 small-M: out[M x 128] = (A*ascale) @ W + bias, 8 rows/block ----------
__global__ __launch_bounds__(256) void k_gemm2s(const float* __restrict__ A,
                                                const float* __restrict__ W,
                                                const float* __restrict__ bias,
                                                float* __restrict__ out, int M, float ascale) {
  __shared__ float As[8][128];
  int tid = threadIdx.x;
  int row0 = blockIdx.x * 8;
  {
    int r = tid >> 5, c4 = (tid & 31) * 4;
    float4 v = make_float4(0.f, 0.f, 0.f, 0.f);
    if (row0 + r < M) v = *(const float4*)&A[(size_t)(row0 + r) * 128 + c4];
    *(float4*)&As[r][c4] = make_float4(v.x * ascale, v.y * ascale, v.z * ascale, v.w * ascale);
  }
  __syncthreads();
  int r = tid >> 5, c0 = (tid & 31) * 4;
  float acc0 = 0.f, acc1 = 0.f, acc2 = 0.f, acc3 = 0.f;
  for (int k = 0; k < 128; ++k) {
    float a = As[r][k];
    float4 wv = *(const float4*)&W[(size_t)k * 128 + c0];
    acc0 = fmaf(a, wv.x, acc0); acc1 = fmaf(a, wv.y, acc1);
    acc2 = fmaf(a, wv.z, acc2); acc3 = fmaf(a, wv.w, acc3);
  }
  if (row0 + r < M) {
    float4 o;
    o.x = acc0 + bias[c0]; o.y = acc1 + bias[c0 + 1];
    o.z = acc2 + bias[c0 + 2]; o.w = acc3 + bias[c0 + 3];
    *(float4*)&out[(size_t)(row0 + r) * 128 + c0] = o;
  }
}

extern "C" void kernel_launch(void* const* d_in, const int* in_sizes, int n_in,
                              void* d_out, int out_size, void* d_ws, size_t ws_size,
                              hipStream_t stream) {
  const float* x  = (const float*)d_in[0];
  const void* edges = d_in[1];
  const float* W1 = (const float*)d_in[3];
  const float* b1 = (const float*)d_in[4];
  const float* W2 = (const float*)d_in[5];
  const float* b2 = (const float*)d_in[6];
  float* out = (float*)d_out;

  // workspace layout (bytes), ~40.7 MB total
  char* ws = (char*)d_ws;
  float* poolsum  = (float*)(ws + 0);          // 256000  (zeroed in k_ordercvt)
  int*   hist     = (int*)(ws + 256000);       // 400384
  int*   histS    = (int*)(ws + 656384);       // 400384 (block-exclusive)
  int*   bsums    = (int*)(ws + 1056768);      // 2048   (raw block sums)
  int*   rowstart = (int*)(ws + 1058816);      // 400016
  float* dinv     = (float*)(ws + 1458832);    // 400000
  int*   order    = (int*)(ws + 1858832);      // 400000
  unsigned int* W1t = (unsigned int*)(ws + 2258832);     // 32768 (bf16 W1^T)
  unsigned int* sorted = (unsigned int*)(ws + 2291600);  // 6.4 MB
  int*   csr      = (int*)(ws + 8691600);      // 6.4 MB
  void*  xs8      = (void*)(ws + 15091600);    // 12.8 MB  fp8(8*dinv*x)
  void*  h1s8     = (void*)(ws + 27891600);    // 12.8 MB  fp8(16*dinv*h1)

  const int NH = NBK * NBLK;  // 100096 histogram entries

  k_hist1<<<NBLK, 256, 0, stream>>>(edges, hist);
  k_scan_block<<<NSB, 256, 0, stream>>>(hist, histS, bsums, NH);
  k_scatter<<<NBLK, 256, 0, stream>>>(edges, histS, bsums, sorted);
  k_passB2<<<NBK, 256, 0, stream>>>(sorted, histS, bsums, rowstart, dinv, csr);
  // order (descending degree, LPT) + xs8 = fp8(8*dinv*x) + W1t = bf16(W1^T) + zero poolsum
  k_ordercvt<<<NG, 256, 0, stream>>>(rowstart, dinv, (const float4*)x, (uint2*)xs8,
                                     W1, W1t, order, poolsum);

  // conv1 fused: h1s8 = fp8( 16 * dinv * relu( Agg(x) @ W1 + b1 ) )
  k_agg1g<<<NN / 16, 256, 0, stream>>>((const uint2*)xs8, W1t, b1, (uint2*)h1s8,
                                       rowstart, csr, dinv, order);
  // conv2 fused with pool: poolsum = 16 * sum_graph( dinv*(h1s self+gather) )
  k_agg2p<<<NN / 16, 256, 0, stream>>>((const uint2*)h1s8, poolsum, rowstart, csr, dinv, order);
  // out = (poolsum/(200*16)) @ W2 + b2
  k_gemm2s<<<(NG + 7) / 8, 256, 0, stream>>>(poolsum, W2, b2, out, NG, 1.f / 3200.f);
}